// Round 3
// baseline (460.203 us; speedup 1.0000x reference)
//
#include <hip/hip_runtime.h>

typedef __bf16 bf16;
typedef __bf16 bf16x8 __attribute__((ext_vector_type(8)));
typedef float floatx4 __attribute__((ext_vector_type(4)));

#define BATCH 128
#define SEQ   2048
#define HID   128
#define TWOH  256
#define CH    128
#define NCH   16
#define MTOT  (BATCH * SEQ)    // 262144

__device__ __forceinline__ float fast_tanh(float x) {
    float e = __builtin_amdgcn_exp2f(2.88539008177793f * x);
    return 1.0f - 2.0f * __builtin_amdgcn_rcpf(e + 1.0f);
}
__device__ __forceinline__ float fast_sigmoid(float x) {
    return __builtin_amdgcn_rcpf(1.0f + __builtin_amdgcn_exp2f(-1.44269504088896f * x));
}

union PK8 { uint4 u; bf16 h[8]; };
union PK4 { unsigned long long u; bf16 h[4]; };

// ---- one-time f32 -> bf16 conversion of Wx2h (both layers) ----
__global__ __launch_bounds__(256) void convert_w_k(const float* __restrict__ W,
                                                   bf16* __restrict__ Wb) {
    int i = blockIdx.x * 256 + threadIdx.x;   // 16384 float4 groups
    float4 v = ((const float4*)W)[i];
    PK4 pk;
    pk.h[0] = (bf16)v.x; pk.h[1] = (bf16)v.y;
    pk.h[2] = (bf16)v.z; pk.h[3] = (bf16)v.w;
    ((unsigned long long*)Wb)[i] = pk.u;
}

// ---- GEMM + tanh + fused per-chunk column sums ----
// block = one (b,chunk): 128 rows x 256 cols, K=128. 256 thr = 2x2 waves.
// A staged in LDS (32KB, XOR-swizzled); B (weights) read directly from
// global per k-step: 64KB/layer stays hot in L1/L2, frag loads are
// full-line coalesced (n=l16 rows, quad covers 64B contiguous).
// MFMA operands swapped => D transposed => 4 acc regs = 4 contiguous G cols.
template <bool AF32>
__global__ __launch_bounds__(256, 4) void gemm_tanh_k(const void* __restrict__ Aptr,
                                                      const bf16* __restrict__ Wb,
                                                      bf16* __restrict__ G,
                                                      float* __restrict__ P) {
    __shared__ bf16 As[128 * 128];
    __shared__ float psum[2][256];

    const int tid  = threadIdx.x;
    const int lane = tid & 63;
    const int wid  = tid >> 6;
    const int wr   = wid >> 1;
    const int wc   = wid & 1;
    const long rowBase = (long)blockIdx.x * 128;

    if (AF32) {
        const float4* A4 = (const float4*)((const float*)Aptr + rowBase * HID);
        #pragma unroll
        for (int it = 0; it < 16; ++it) {
            int i  = it * 256 + tid;
            int r  = i >> 5;
            int c4 = i & 31;
            float4 v = A4[i];
            int g = c4 >> 1, hf = c4 & 1;
            PK4 pk;
            pk.h[0] = (bf16)v.x; pk.h[1] = (bf16)v.y;
            pk.h[2] = (bf16)v.z; pk.h[3] = (bf16)v.w;
            *(unsigned long long*)&As[r * 128 + ((g ^ (r & 7)) << 3) + (hf << 2)] = pk.u;
        }
    } else {
        const uint4* A8 = (const uint4*)((const bf16*)Aptr + rowBase * HID);
        #pragma unroll
        for (int it = 0; it < 8; ++it) {
            int i = it * 256 + tid;
            int r = i >> 4;
            int g = i & 15;
            uint4 v = A8[i];
            *(uint4*)&As[r * 128 + ((g ^ (r & 7)) << 3)] = v;
        }
    }
    __syncthreads();

    const int quad = lane >> 4;
    const int l16  = lane & 15;

    #pragma unroll
    for (int half = 0; half < 2; ++half) {
        // this wave's 64-col stripe of W for this half, rows n, row-major K
        const bf16* Wh = Wb + (half * 128 + wc * 64) * HID;

        floatx4 acc[4][4];
        #pragma unroll
        for (int a = 0; a < 4; ++a)
            #pragma unroll
            for (int b2 = 0; b2 < 4; ++b2) acc[a][b2] = (floatx4){0.f, 0.f, 0.f, 0.f};

        #pragma unroll
        for (int kk = 0; kk < 128; kk += 32) {
            bf16x8 af[4], bfr[4];
            int kg = (kk >> 3) + quad;
            #pragma unroll
            for (int ni = 0; ni < 4; ++ni)
                bfr[ni] = *(const bf16x8*)&Wh[(ni * 16 + l16) * HID + kk + quad * 8];
            #pragma unroll
            for (int mi = 0; mi < 4; ++mi) {
                int r = wr * 64 + mi * 16 + l16;
                af[mi] = *(const bf16x8*)&As[r * 128 + ((kg ^ (r & 7)) << 3)];
            }
            #pragma unroll
            for (int mi = 0; mi < 4; ++mi)
                #pragma unroll
                for (int ni = 0; ni < 4; ++ni)
                    acc[mi][ni] = __builtin_amdgcn_mfma_f32_16x16x32_bf16(
                        bfr[ni], af[mi], acc[mi][ni], 0, 0, 0);  // swapped => D^T
        }

        // epilogue: tanh -> bf16, packed 8B stores; accumulate column sums
        float ps[4][4];
        #pragma unroll
        for (int ni = 0; ni < 4; ++ni)
            #pragma unroll
            for (int rr = 0; rr < 4; ++rr) ps[ni][rr] = 0.f;

        #pragma unroll
        for (int mi = 0; mi < 4; ++mi) {
            int row = (int)rowBase + wr * 64 + mi * 16 + l16;
            #pragma unroll
            for (int ni = 0; ni < 4; ++ni) {
                int col = half * 128 + wc * 64 + ni * 16 + quad * 4;
                PK4 pk;
                #pragma unroll
                for (int rr = 0; rr < 4; ++rr) {
                    bf16 bv = (bf16)fast_tanh(acc[mi][ni][rr]);
                    pk.h[rr] = bv;
                    ps[ni][rr] += (float)bv;   // sum the rounded value
                }
                *(unsigned long long*)&G[(long)row * TWOH + col] = pk.u;
            }
        }
        // reduce over the 16 l16-lanes (this wave's 64 rows done in-thread over mi)
        #pragma unroll
        for (int ni = 0; ni < 4; ++ni)
            #pragma unroll
            for (int rr = 0; rr < 4; ++rr) {
                float v = ps[ni][rr];
                v += __shfl_xor(v, 1);
                v += __shfl_xor(v, 2);
                v += __shfl_xor(v, 4);
                v += __shfl_xor(v, 8);
                if (l16 == 0)
                    psum[wr][half * 128 + wc * 64 + ni * 16 + quad * 4 + rr] = v;
            }
    }
    __syncthreads();
    P[((long)blockIdx.x << 8) + tid] = psum[0][tid] + psum[1][tid];
}

// in-place exclusive scan over the NCH chunks, per (b, ch); loads batched
__global__ __launch_bounds__(256) void scan_partials_k(float* __restrict__ P) {
    int ch = threadIdx.x;
    long b = blockIdx.x;
    float v[NCH];
    #pragma unroll
    for (int c = 0; c < NCH; ++c) v[c] = P[((b * NCH + c) << 8) + ch];
    float run = 0.f;
    #pragma unroll
    for (int c = 0; c < NCH; ++c) {
        float t = v[c];
        P[((b * NCH + c) << 8) + ch] = run;
        run += t;
    }
}

// h(t,j) = P2 - relu(P1)*g2, vectorized 8 ch/thread, per-(b,chunk) block.
// 256 thr = 16 t-slices x 16 ch-groups; LDS scan over slices.
__global__ __launch_bounds__(256) void compute_h_k(const bf16* __restrict__ G,
                                                   const float* __restrict__ P,
                                                   bf16* __restrict__ Hb) {
    __shared__ float sub1[16][128];
    __shared__ float sub2[16][128];
    const int tid = threadIdx.x;
    const int cg = tid & 15, ts = tid >> 4;
    const long blk = blockIdx.x;
    const long gbase = blk * CH * TWOH + cg * 8;

    float s1[8], s2[8];
    #pragma unroll
    for (int r = 0; r < 8; ++r) { s1[r] = 0.f; s2[r] = 0.f; }
    #pragma unroll
    for (int i = 0; i < 8; ++i) {
        int t = ts * 8 + i;
        PK8 a, b;
        a.u = *(const uint4*)&G[gbase + (long)t * TWOH];
        b.u = *(const uint4*)&G[gbase + (long)t * TWOH + 128];
        #pragma unroll
        for (int r = 0; r < 8; ++r) { s1[r] += (float)a.h[r]; s2[r] += (float)b.h[r]; }
    }
    #pragma unroll
    for (int r = 0; r < 8; ++r) { sub1[ts][cg * 8 + r] = s1[r]; sub2[ts][cg * 8 + r] = s2[r]; }
    __syncthreads();
    if (tid < 128) {
        float run = 0.f;
        #pragma unroll
        for (int c = 0; c < 16; ++c) { float v = sub1[c][tid]; sub1[c][tid] = run; run += v; }
    } else {
        int j = tid - 128;
        float run = 0.f;
        #pragma unroll
        for (int c = 0; c < 16; ++c) { float v = sub2[c][j]; sub2[c][j] = run; run += v; }
    }
    __syncthreads();

    float P1[8], P2[8];
    #pragma unroll
    for (int r = 0; r < 8; ++r) {
        P1[r] = P[(blk << 8) + cg * 8 + r] + sub1[ts][cg * 8 + r];
        P2[r] = P[(blk << 8) + 128 + cg * 8 + r] + sub2[ts][cg * 8 + r];
    }
    #pragma unroll
    for (int i = 0; i < 8; ++i) {
        int t = ts * 8 + i;
        PK8 a, b, hh;
        a.u = *(const uint4*)&G[gbase + (long)t * TWOH];
        b.u = *(const uint4*)&G[gbase + (long)t * TWOH + 128];
        #pragma unroll
        for (int r = 0; r < 8; ++r) {
            float g1 = (float)a.h[r], g2 = (float)b.h[r];
            P1[r] += g1; P2[r] += g2;
            hh.h[r] = (bf16)(P2[r] - fmaxf(P1[r], 0.f) * g2);
        }
        *(uint4*)&Hb[(blk * CH + t) * HID + cg * 8] = hh.u;
    }
}

// layer-1 scan + fc dot + double sigmoid + masked sq-err, fused per (b,chunk)
__global__ __launch_bounds__(256) void final_loss_k(const bf16* __restrict__ G,
                                                    const float* __restrict__ P,
                                                    const float* __restrict__ Wfc,
                                                    const int* __restrict__ xlen,
                                                    const float* __restrict__ xlab,
                                                    float* __restrict__ out) {
    __shared__ float sub1[16][128];
    __shared__ float sub2[16][128];
    __shared__ float red[4];
    const int tid = threadIdx.x;
    const int lane = tid & 63;
    const int cg = tid & 15, ts = tid >> 4;
    const long blk = blockIdx.x;
    const int b = (int)(blk >> 4), chunk = (int)(blk & 15);
    const long gbase = blk * CH * TWOH + cg * 8;

    float s1[8], s2[8];
    #pragma unroll
    for (int r = 0; r < 8; ++r) { s1[r] = 0.f; s2[r] = 0.f; }
    #pragma unroll
    for (int i = 0; i < 8; ++i) {
        int t = ts * 8 + i;
        PK8 a, bb;
        a.u = *(const uint4*)&G[gbase + (long)t * TWOH];
        bb.u = *(const uint4*)&G[gbase + (long)t * TWOH + 128];
        #pragma unroll
        for (int r = 0; r < 8; ++r) { s1[r] += (float)a.h[r]; s2[r] += (float)bb.h[r]; }
    }
    #pragma unroll
    for (int r = 0; r < 8; ++r) { sub1[ts][cg * 8 + r] = s1[r]; sub2[ts][cg * 8 + r] = s2[r]; }
    __syncthreads();
    if (tid < 128) {
        float run = 0.f;
        #pragma unroll
        for (int c = 0; c < 16; ++c) { float v = sub1[c][tid]; sub1[c][tid] = run; run += v; }
    } else {
        int j = tid - 128;
        float run = 0.f;
        #pragma unroll
        for (int c = 0; c < 16; ++c) { float v = sub2[c][j]; sub2[c][j] = run; run += v; }
    }
    __syncthreads();

    float w0[8], w1[8], P1[8], P2[8];
    #pragma unroll
    for (int r = 0; r < 8; ++r) {
        w0[r] = Wfc[2 * HID + cg * 8 + r];
        w1[r] = Wfc[3 * HID + cg * 8 + r];
        P1[r] = P[(blk << 8) + cg * 8 + r] + sub1[ts][cg * 8 + r];
        P2[r] = P[(blk << 8) + 128 + cg * 8 + r] + sub2[ts][cg * 8 + r];
    }
    const int xl = xlen[b];
    const float lab = xlab[b];
    float lsum = 0.f;
    #pragma unroll
    for (int i = 0; i < 8; ++i) {
        int t = ts * 8 + i;
        PK8 a, bb;
        a.u = *(const uint4*)&G[gbase + (long)t * TWOH];
        bb.u = *(const uint4*)&G[gbase + (long)t * TWOH + 128];
        float z0 = 0.f, z1 = 0.f;
        #pragma unroll
        for (int r = 0; r < 8; ++r) {
            float g1 = (float)a.h[r], g2 = (float)bb.h[r];
            P1[r] += g1; P2[r] += g2;
            float h = P2[r] - fmaxf(P1[r], 0.f) * g2;
            z0 += h * w0[r]; z1 += h * w1[r];
        }
        #pragma unroll
        for (int m = 1; m < 16; m <<= 1) { z0 += __shfl_xor(z0, m); z1 += __shfl_xor(z1, m); }
        if (cg == 0) {
            float o1 = fast_sigmoid(z1 - z0);
            float sg = fast_sigmoid(o1);
            int tg = chunk * CH + t;
            float d = lab - sg;
            if (tg < xl) lsum += d * d;
        }
    }
    lsum += __shfl_xor(lsum, 16);
    lsum += __shfl_xor(lsum, 32);
    if (lane == 0) red[tid >> 6] = lsum;
    __syncthreads();
    if (tid == 0) atomicAdd(out, red[0] + red[1] + red[2] + red[3]);
}

extern "C" void kernel_launch(void* const* d_in, const int* in_sizes, int n_in,
                              void* d_out, int out_size, void* d_ws, size_t ws_size,
                              hipStream_t stream) {
    const float* x    = (const float*)d_in[0];
    const int*   xlen = (const int*)d_in[1];
    const float* xlab = (const float*)d_in[2];
    const float* Wx2h = (const float*)d_in[3];  // [2,256,128] f32
    const float* Wfc  = (const float*)d_in[4];  // [2,2,128] f32
    float* out = (float*)d_out;

    char* ws = (char*)d_ws;
    bf16*  G  = (bf16*)ws;                                            // 128 MiB
    bf16*  Hb = (bf16*)(ws + (size_t)MTOT * TWOH * 2);                // 64 MiB
    float* P  = (float*)(ws + (size_t)MTOT * TWOH * 2 + (size_t)MTOT * HID * 2);  // 2 MiB
    bf16*  Wb = (bf16*)((char*)P + (size_t)BATCH * NCH * TWOH * 4);   // 128 KiB

    hipMemsetAsync(d_out, 0, sizeof(float), stream);
    convert_w_k<<<64, 256, 0, stream>>>(Wx2h, Wb);

    gemm_tanh_k<true><<<MTOT / 128, 256, 0, stream>>>(x, Wb, G, P);
    scan_partials_k<<<BATCH, 256, 0, stream>>>(P);
    compute_h_k<<<MTOT / 128, 256, 0, stream>>>(G, P, Hb);

    gemm_tanh_k<false><<<MTOT / 128, 256, 0, stream>>>(Hb, Wb + TWOH * HID, G, P);
    scan_partials_k<<<BATCH, 256, 0, stream>>>(P);
    final_loss_k<<<MTOT / 128, 256, 0, stream>>>(G, P, Wfc, xlen, xlab, out);
}

// Round 4
// 383.413 us; speedup vs baseline: 1.2003x; 1.2003x over previous
//
#include <hip/hip_runtime.h>

typedef __bf16 bf16;
typedef __bf16 bf16x8 __attribute__((ext_vector_type(8)));
typedef float floatx4 __attribute__((ext_vector_type(4)));

#define BATCH 128
#define SEQ   2048
#define HID   128
#define TWOH  256
#define CH    128
#define NCH   16
#define MTOT  (BATCH * SEQ)    // 262144

__device__ __forceinline__ float fast_tanh(float x) {
    float e = __builtin_amdgcn_exp2f(2.88539008177793f * x);
    return 1.0f - 2.0f * __builtin_amdgcn_rcpf(e + 1.0f);
}
__device__ __forceinline__ float fast_sigmoid(float x) {
    return __builtin_amdgcn_rcpf(1.0f + __builtin_amdgcn_exp2f(-1.44269504088896f * x));
}

union PK4 { unsigned long long u; bf16 h[4]; };

// ---- one-time f32 -> bf16 conversion of Wx2h (both layers) ----
__global__ __launch_bounds__(256) void convert_w_k(const float* __restrict__ W,
                                                   bf16* __restrict__ Wb) {
    int i = blockIdx.x * 256 + threadIdx.x;   // 16384 float4 groups
    float4 v = ((const float4*)W)[i];
    PK4 pk;
    pk.h[0] = (bf16)v.x; pk.h[1] = (bf16)v.y;
    pk.h[2] = (bf16)v.z; pk.h[3] = (bf16)v.w;
    ((unsigned long long*)Wb)[i] = pk.u;
}

// ===========================================================================
// Fused GEMM kernel. Block = one (b,chunk): 128 rows(t) x 256 cols, K=128.
// A and W both staged in LDS (XOR-swizzled), W restaged per 128-col half.
// Non-swapped MFMA: C row = wr*64+mi*16+quad*4+rr, col = wc*64+ni*16+l16
// (+half*128). Rows of a column scan as: rr (in-thread) -> quad (shfl_up)
// -> mi (in-thread chain) -> wr (LDS). Col pair (c, c+128) lands in the
// SAME thread across the two halves, so h = P2 - relu(P1)*g2 is local.
// MODE 0: per-chunk column sums only (PASS1)
// MODE 1: in-tile prefix + h -> Hb (layer-0 PASS2)
// MODE 2: in-tile prefix + h + fc dot + sigmoids + masked loss (layer-1 PASS2)
// ===========================================================================
template <int MODE, bool AF32>
__global__ __launch_bounds__(256, 2) void fused_k(const void* __restrict__ Aptr,
                                                  const bf16* __restrict__ Wb,
                                                  const float* __restrict__ Pbase,
                                                  float* __restrict__ Pout,
                                                  bf16* __restrict__ Hb,
                                                  const float* __restrict__ Wfc,
                                                  const int* __restrict__ xlen,
                                                  const float* __restrict__ xlab,
                                                  float* __restrict__ out) {
    __shared__ bf16 As[128 * 128];          // 32 KB
    __shared__ bf16 Bs[128 * 128];          // 32 KB
    __shared__ float aux[512];              // MODE0: psum[2][256]; MODE>=1: colsum[128]
    __shared__ float zbuf[2][128][2];       // MODE2
    __shared__ float red[2];

    const int tid  = threadIdx.x;
    const int lane = tid & 63;
    const int wid  = tid >> 6;
    const int wr   = wid >> 1;
    const int wc   = wid & 1;
    const int quad = lane >> 4;
    const int l16  = lane & 15;
    const long blk = blockIdx.x;
    const long rowBase = blk * 128;

    // ---- stage A ----
    if (AF32) {
        const float4* A4 = (const float4*)((const float*)Aptr + rowBase * HID);
        #pragma unroll
        for (int it = 0; it < 16; ++it) {
            int i  = it * 256 + tid;
            int r  = i >> 5;
            int c4 = i & 31;
            float4 v = A4[i];
            int g = c4 >> 1, hf = c4 & 1;
            PK4 pk;
            pk.h[0] = (bf16)v.x; pk.h[1] = (bf16)v.y;
            pk.h[2] = (bf16)v.z; pk.h[3] = (bf16)v.w;
            *(unsigned long long*)&As[r * 128 + ((g ^ (r & 7)) << 3) + (hf << 2)] = pk.u;
        }
    } else {
        const uint4* A8 = (const uint4*)((const bf16*)Aptr + rowBase * HID);
        #pragma unroll
        for (int it = 0; it < 8; ++it) {
            int i = it * 256 + tid;
            int r = i >> 4;
            int g = i & 15;
            uint4 v = A8[i];
            *(uint4*)&As[r * 128 + ((g ^ (r & 7)) << 3)] = v;
        }
    }

    float p1[4][4][4];   // half-0 global-inclusive prefixes (MODE>=1)
    float h[4][4][4];    // tanh values / h values

    #pragma unroll
    for (int half = 0; half < 2; ++half) {
        __syncthreads();   // A staged (half0) / Bs+aux reads done (half1)
        // ---- stage W half ----
        {
            const uint4* W8 = (const uint4*)(Wb + half * 128 * HID);
            #pragma unroll
            for (int it = 0; it < 8; ++it) {
                int i = it * 256 + tid;
                int r = i >> 4;
                int g = i & 15;
                uint4 v = W8[i];
                *(uint4*)&Bs[r * 128 + ((g ^ (r & 7)) << 3)] = v;
            }
        }
        __syncthreads();

        // ---- MFMA ----
        floatx4 acc[4][4];
        #pragma unroll
        for (int a = 0; a < 4; ++a)
            #pragma unroll
            for (int b2 = 0; b2 < 4; ++b2) acc[a][b2] = (floatx4){0.f, 0.f, 0.f, 0.f};

        #pragma unroll
        for (int kk = 0; kk < 128; kk += 32) {
            bf16x8 af[4], bfr[4];
            int kg = (kk >> 3) + quad;
            #pragma unroll
            for (int mi = 0; mi < 4; ++mi) {
                int r = wr * 64 + mi * 16 + l16;
                af[mi] = *(const bf16x8*)&As[r * 128 + ((kg ^ (r & 7)) << 3)];
            }
            #pragma unroll
            for (int ni = 0; ni < 4; ++ni) {
                int n = wc * 64 + ni * 16 + l16;
                bfr[ni] = *(const bf16x8*)&Bs[n * 128 + ((kg ^ (n & 7)) << 3)];
            }
            #pragma unroll
            for (int mi = 0; mi < 4; ++mi)
                #pragma unroll
                for (int ni = 0; ni < 4; ++ni)
                    acc[mi][ni] = __builtin_amdgcn_mfma_f32_16x16x32_bf16(
                        af[mi], bfr[ni], acc[mi][ni], 0, 0, 0);
        }

        // ---- tanh (f32, unrounded) ----
        float g2loc[4][4][4];
        #pragma unroll
        for (int mi = 0; mi < 4; ++mi)
            #pragma unroll
            for (int ni = 0; ni < 4; ++ni)
                #pragma unroll
                for (int rr = 0; rr < 4; ++rr)
                    g2loc[mi][ni][rr] = fast_tanh(acc[mi][ni][rr]);

        if (MODE == 0) {
            // column sums over this wave's 64 rows
            #pragma unroll
            for (int ni = 0; ni < 4; ++ni) {
                float cs = 0.f;
                #pragma unroll
                for (int mi = 0; mi < 4; ++mi)
                    #pragma unroll
                    for (int rr = 0; rr < 4; ++rr) cs += g2loc[mi][ni][rr];
                cs += __shfl_xor(cs, 16);
                cs += __shfl_xor(cs, 32);
                if (quad == 0)
                    aux[wr * 256 + half * 128 + wc * 64 + ni * 16 + l16] = cs;
            }
        } else {
            // ---- in-tile inclusive prefix over rows, per column ----
            float pref[4][4][4];
            #pragma unroll
            for (int ni = 0; ni < 4; ++ni) {
                float mibase = 0.f;
                #pragma unroll
                for (int mi = 0; mi < 4; ++mi) {
                    float s0 = g2loc[mi][ni][0];
                    float s1 = s0 + g2loc[mi][ni][1];
                    float s2 = s1 + g2loc[mi][ni][2];
                    float s3 = s2 + g2loc[mi][ni][3];
                    float tot = s3;
                    float xq = tot;
                    float t = __shfl_up(xq, 16);
                    if (quad >= 1) xq += t;
                    t = __shfl_up(xq, 32);
                    if (quad >= 2) xq += t;
                    float excl = mibase + xq - tot;
                    pref[mi][ni][0] = excl + s0;
                    pref[mi][ni][1] = excl + s1;
                    pref[mi][ni][2] = excl + s2;
                    pref[mi][ni][3] = excl + s3;
                    mibase += __shfl(xq, 48 + l16);   // quad-3 inclusive total
                }
                // wave total for this col -> LDS (wr=0 writes, wr=1 adds)
                if (wr == 0 && quad == 0)
                    aux[wc * 64 + ni * 16 + l16] = mibase;
            }
            __syncthreads();
            #pragma unroll
            for (int ni = 0; ni < 4; ++ni) {
                int col = half * 128 + wc * 64 + ni * 16 + l16;
                float off = Pbase[(blk << 8) + col];
                if (wr) off += aux[wc * 64 + ni * 16 + l16];
                #pragma unroll
                for (int mi = 0; mi < 4; ++mi)
                    #pragma unroll
                    for (int rr = 0; rr < 4; ++rr)
                        pref[mi][ni][rr] += off;
            }
            if (half == 0) {
                #pragma unroll
                for (int mi = 0; mi < 4; ++mi)
                    #pragma unroll
                    for (int ni = 0; ni < 4; ++ni)
                        #pragma unroll
                        for (int rr = 0; rr < 4; ++rr)
                            p1[mi][ni][rr] = pref[mi][ni][rr];
            } else {
                #pragma unroll
                for (int mi = 0; mi < 4; ++mi)
                    #pragma unroll
                    for (int ni = 0; ni < 4; ++ni)
                        #pragma unroll
                        for (int rr = 0; rr < 4; ++rr)
                            h[mi][ni][rr] = pref[mi][ni][rr] -
                                fmaxf(p1[mi][ni][rr], 0.f) * g2loc[mi][ni][rr];
            }
        }
    }

    if (MODE == 0) {
        __syncthreads();
        Pout[(blk << 8) + tid] = aux[tid] + aux[256 + tid];
    } else if (MODE == 1) {
        // store h as bf16, row-major [row][128]
        #pragma unroll
        for (int mi = 0; mi < 4; ++mi)
            #pragma unroll
            for (int rr = 0; rr < 4; ++rr) {
                long row = rowBase + wr * 64 + mi * 16 + quad * 4 + rr;
                #pragma unroll
                for (int ni = 0; ni < 4; ++ni)
                    Hb[row * HID + wc * 64 + ni * 16 + l16] = (bf16)h[mi][ni][rr];
            }
    } else {
        // fc dot + sigmoids + masked squared error
        float w0[4], w1[4];
        #pragma unroll
        for (int ni = 0; ni < 4; ++ni) {
            int c = wc * 64 + ni * 16 + l16;
            w0[ni] = Wfc[2 * HID + c];
            w1[ni] = Wfc[3 * HID + c];
        }
        #pragma unroll
        for (int mi = 0; mi < 4; ++mi)
            #pragma unroll
            for (int rr = 0; rr < 4; ++rr) {
                float z0 = 0.f, z1 = 0.f;
                #pragma unroll
                for (int ni = 0; ni < 4; ++ni) {
                    z0 += h[mi][ni][rr] * w0[ni];
                    z1 += h[mi][ni][rr] * w1[ni];
                }
                z0 += __shfl_xor(z0, 1); z1 += __shfl_xor(z1, 1);
                z0 += __shfl_xor(z0, 2); z1 += __shfl_xor(z1, 2);
                z0 += __shfl_xor(z0, 4); z1 += __shfl_xor(z1, 4);
                z0 += __shfl_xor(z0, 8); z1 += __shfl_xor(z1, 8);
                if (l16 == 0) {
                    int row = wr * 64 + mi * 16 + quad * 4 + rr;
                    zbuf[wc][row][0] = z0;
                    zbuf[wc][row][1] = z1;
                }
            }
        __syncthreads();
        float lsum = 0.f;
        if (tid < 128) {
            int row = tid;
            int b = (int)(blk >> 4), chunk = (int)(blk & 15);
            float z0 = zbuf[0][row][0] + zbuf[1][row][0];
            float z1 = zbuf[0][row][1] + zbuf[1][row][1];
            float o1 = fast_sigmoid(z1 - z0);
            float sg = fast_sigmoid(o1);
            float d = xlab[b] - sg;
            if (chunk * CH + row < xlen[b]) lsum = d * d;
            lsum += __shfl_xor(lsum, 1);
            lsum += __shfl_xor(lsum, 2);
            lsum += __shfl_xor(lsum, 4);
            lsum += __shfl_xor(lsum, 8);
            lsum += __shfl_xor(lsum, 16);
            lsum += __shfl_xor(lsum, 32);
            if (lane == 0) red[tid >> 6] = lsum;
        }
        __syncthreads();
        if (tid == 0) atomicAdd(out, red[0] + red[1]);
    }
}

// in-place exclusive scan over the NCH chunks, per (b, ch)
__global__ __launch_bounds__(256) void scan_partials_k(float* __restrict__ P) {
    int ch = threadIdx.x;
    long b = blockIdx.x;
    float v[NCH];
    #pragma unroll
    for (int c = 0; c < NCH; ++c) v[c] = P[((b * NCH + c) << 8) + ch];
    float run = 0.f;
    #pragma unroll
    for (int c = 0; c < NCH; ++c) {
        float t = v[c];
        P[((b * NCH + c) << 8) + ch] = run;
        run += t;
    }
}

extern "C" void kernel_launch(void* const* d_in, const int* in_sizes, int n_in,
                              void* d_out, int out_size, void* d_ws, size_t ws_size,
                              hipStream_t stream) {
    const float* x    = (const float*)d_in[0];
    const int*   xlen = (const int*)d_in[1];
    const float* xlab = (const float*)d_in[2];
    const float* Wx2h = (const float*)d_in[3];  // [2,256,128] f32
    const float* Wfc  = (const float*)d_in[4];  // [2,2,128] f32
    float* out = (float*)d_out;

    char* ws = (char*)d_ws;
    bf16*  Hb = (bf16*)ws;                                   // 64 MiB
    float* P  = (float*)(ws + (size_t)MTOT * HID * 2);       // 2 MiB
    bf16*  Wb = (bf16*)((char*)P + (size_t)BATCH * NCH * TWOH * 4);  // 128 KiB

    hipMemsetAsync(d_out, 0, sizeof(float), stream);
    convert_w_k<<<64, 256, 0, stream>>>(Wx2h, Wb);

    // layer 0: pass1 (chunk sums) -> scan -> pass2 (h0 -> Hb)
    fused_k<0, true><<<MTOT / 128, 256, 0, stream>>>(x, Wb, nullptr, P, nullptr,
                                                     nullptr, nullptr, nullptr, nullptr);
    scan_partials_k<<<BATCH, 256, 0, stream>>>(P);
    fused_k<1, true><<<MTOT / 128, 256, 0, stream>>>(x, Wb, P, nullptr, Hb,
                                                     nullptr, nullptr, nullptr, nullptr);
    // layer 1: pass1 -> scan -> pass2 (loss)
    fused_k<0, false><<<MTOT / 128, 256, 0, stream>>>(Hb, Wb + TWOH * HID, nullptr, P,
                                                      nullptr, nullptr, nullptr, nullptr, nullptr);
    scan_partials_k<<<BATCH, 256, 0, stream>>>(P);
    fused_k<2, false><<<MTOT / 128, 256, 0, stream>>>(Hb, Wb + TWOH * HID, P, nullptr,
                                                      nullptr, Wfc, xlen, xlab, out);
}

// Round 5
// 376.968 us; speedup vs baseline: 1.2208x; 1.0171x over previous
//
#include <hip/hip_runtime.h>

typedef __bf16 bf16;
typedef __bf16 bf16x8 __attribute__((ext_vector_type(8)));
typedef float floatx4 __attribute__((ext_vector_type(4)));

#define BATCH 128
#define SEQ   2048
#define HID   128
#define TWOH  256
#define CH    128
#define NCH   16
#define MTOT  (BATCH * SEQ)    // 262144

__device__ __forceinline__ float fast_tanh(float x) {
    float e = __builtin_amdgcn_exp2f(2.88539008177793f * x);
    return 1.0f - 2.0f * __builtin_amdgcn_rcpf(e + 1.0f);
}
__device__ __forceinline__ float fast_sigmoid(float x) {
    return __builtin_amdgcn_rcpf(1.0f + __builtin_amdgcn_exp2f(-1.44269504088896f * x));
}

union PK4 { unsigned long long u; bf16 h[4]; };

// ---- one-time f32 -> bf16 conversion of Wx2h (both layers) ----
__global__ __launch_bounds__(256) void convert_w_k(const float* __restrict__ W,
                                                   bf16* __restrict__ Wb) {
    int i = blockIdx.x * 256 + threadIdx.x;   // 16384 float4 groups
    float4 v = ((const float4*)W)[i];
    PK4 pk;
    pk.h[0] = (bf16)v.x; pk.h[1] = (bf16)v.y;
    pk.h[2] = (bf16)v.z; pk.h[3] = (bf16)v.w;
    ((unsigned long long*)Wb)[i] = pk.u;
}

// ===========================================================================
// Fused GEMM kernel. Block = one (b,chunk): 128 rows(t) x 256 cols, K=128.
// 512 threads = 8 waves: wr = wid>>2 (row 64-stripe), wc = wid&3 (col
// 32-stripe within the 128-col half). Per-thread per half: 16 rows x 2 cols
// => acc[4][2], p1[4][2][4] (32 floats) -- sized to avoid register spill.
// C row = wr*64+mi*16+quad*4+rr, col = half*128+wc*32+ni*16+l16.
// Row scan: rr (in-thread) -> quad (shfl_up) -> mi (chain) -> wr (LDS).
// Col pair (c, c+128) lands in the SAME thread across the two halves.
// MODE 0: per-chunk column sums only (PASS1)
// MODE 1: in-tile prefix + h -> Hb (layer-0 PASS2)
// MODE 2: in-tile prefix + h + fc dot + sigmoids + masked loss (layer-1 PASS2)
// ===========================================================================
template <int MODE, bool AF32>
__global__ __launch_bounds__(512, 4) void fused_k(const void* __restrict__ Aptr,
                                                  const bf16* __restrict__ Wb,
                                                  const float* __restrict__ Pbase,
                                                  float* __restrict__ Pout,
                                                  bf16* __restrict__ Hb,
                                                  const float* __restrict__ Wfc,
                                                  const int* __restrict__ xlen,
                                                  const float* __restrict__ xlab,
                                                  float* __restrict__ out) {
    __shared__ bf16 As[128 * 128];          // 32 KB
    __shared__ bf16 Bs[128 * 128];          // 32 KB
    __shared__ float aux[512];              // MODE0: psum[2][256]; MODE>=1: colsum[128]
    __shared__ float zbuf[4][128][2];       // MODE2
    __shared__ float red[2];

    const int tid  = threadIdx.x;
    const int lane = tid & 63;
    const int wid  = tid >> 6;
    const int wr   = wid >> 2;
    const int wc   = wid & 3;
    const int quad = lane >> 4;
    const int l16  = lane & 15;
    const long blk = blockIdx.x;
    const long rowBase = blk * 128;

    // ---- stage A ----
    if (AF32) {
        const float4* A4 = (const float4*)((const float*)Aptr + rowBase * HID);
        #pragma unroll
        for (int it = 0; it < 8; ++it) {
            int i  = it * 512 + tid;
            int r  = i >> 5;
            int c4 = i & 31;
            float4 v = A4[i];
            int g = c4 >> 1, hf = c4 & 1;
            PK4 pk;
            pk.h[0] = (bf16)v.x; pk.h[1] = (bf16)v.y;
            pk.h[2] = (bf16)v.z; pk.h[3] = (bf16)v.w;
            *(unsigned long long*)&As[r * 128 + ((g ^ (r & 7)) << 3) + (hf << 2)] = pk.u;
        }
    } else {
        const uint4* A8 = (const uint4*)((const bf16*)Aptr + rowBase * HID);
        #pragma unroll
        for (int it = 0; it < 4; ++it) {
            int i = it * 512 + tid;
            int r = i >> 4;
            int g = i & 15;
            uint4 v = A8[i];
            *(uint4*)&As[r * 128 + ((g ^ (r & 7)) << 3)] = v;
        }
    }

    float p1[4][2][4];   // half-0 global-inclusive prefixes (MODE>=1)

    #pragma unroll
    for (int half = 0; half < 2; ++half) {
        __syncthreads();   // A staged (half0) / Bs+aux reads done (half1)
        // ---- stage W half ----
        {
            const uint4* W8 = (const uint4*)(Wb + half * 128 * HID);
            #pragma unroll
            for (int it = 0; it < 4; ++it) {
                int i = it * 512 + tid;
                int r = i >> 4;
                int g = i & 15;
                uint4 v = W8[i];
                *(uint4*)&Bs[r * 128 + ((g ^ (r & 7)) << 3)] = v;
            }
        }
        __syncthreads();

        // ---- MFMA ----
        floatx4 acc[4][2];
        #pragma unroll
        for (int a = 0; a < 4; ++a)
            #pragma unroll
            for (int b2 = 0; b2 < 2; ++b2) acc[a][b2] = (floatx4){0.f, 0.f, 0.f, 0.f};

        #pragma unroll
        for (int kk = 0; kk < 128; kk += 32) {
            bf16x8 af[4], bfr[2];
            int kg = (kk >> 3) + quad;
            #pragma unroll
            for (int mi = 0; mi < 4; ++mi) {
                int r = wr * 64 + mi * 16 + l16;
                af[mi] = *(const bf16x8*)&As[r * 128 + ((kg ^ (r & 7)) << 3)];
            }
            #pragma unroll
            for (int ni = 0; ni < 2; ++ni) {
                int n = wc * 32 + ni * 16 + l16;
                bfr[ni] = *(const bf16x8*)&Bs[n * 128 + ((kg ^ (n & 7)) << 3)];
            }
            #pragma unroll
            for (int mi = 0; mi < 4; ++mi)
                #pragma unroll
                for (int ni = 0; ni < 2; ++ni)
                    acc[mi][ni] = __builtin_amdgcn_mfma_f32_16x16x32_bf16(
                        af[mi], bfr[ni], acc[mi][ni], 0, 0, 0);
        }

        // ---- tanh (f32, unrounded) ----
        float g2[4][2][4];
        #pragma unroll
        for (int mi = 0; mi < 4; ++mi)
            #pragma unroll
            for (int ni = 0; ni < 2; ++ni)
                #pragma unroll
                for (int rr = 0; rr < 4; ++rr)
                    g2[mi][ni][rr] = fast_tanh(acc[mi][ni][rr]);

        if (MODE == 0) {
            #pragma unroll
            for (int ni = 0; ni < 2; ++ni) {
                float cs = 0.f;
                #pragma unroll
                for (int mi = 0; mi < 4; ++mi)
                    #pragma unroll
                    for (int rr = 0; rr < 4; ++rr) cs += g2[mi][ni][rr];
                cs += __shfl_xor(cs, 16);
                cs += __shfl_xor(cs, 32);
                if (quad == 0)
                    aux[wr * 256 + half * 128 + wc * 32 + ni * 16 + l16] = cs;
            }
        } else {
            // ---- in-tile inclusive prefix over rows, per column ----
            float pref[4][2][4];
            #pragma unroll
            for (int ni = 0; ni < 2; ++ni) {
                float mibase = 0.f;
                #pragma unroll
                for (int mi = 0; mi < 4; ++mi) {
                    float s0 = g2[mi][ni][0];
                    float s1 = s0 + g2[mi][ni][1];
                    float s2 = s1 + g2[mi][ni][2];
                    float s3 = s2 + g2[mi][ni][3];
                    float tot = s3;
                    float xq = tot;
                    float t = __shfl_up(xq, 16);
                    if (quad >= 1) xq += t;
                    t = __shfl_up(xq, 32);
                    if (quad >= 2) xq += t;
                    float excl = mibase + xq - tot;
                    pref[mi][ni][0] = excl + s0;
                    pref[mi][ni][1] = excl + s1;
                    pref[mi][ni][2] = excl + s2;
                    pref[mi][ni][3] = excl + s3;
                    mibase += __shfl(xq, 48 + l16);   // quad-3 inclusive total
                }
                if (wr == 0 && quad == 0)
                    aux[wc * 32 + ni * 16 + l16] = mibase;
            }
            __syncthreads();

            if (half == 0) {
                #pragma unroll
                for (int ni = 0; ni < 2; ++ni) {
                    int col = wc * 32 + ni * 16 + l16;
                    float off = Pbase[(blk << 8) + col];
                    if (wr) off += aux[col];
                    #pragma unroll
                    for (int mi = 0; mi < 4; ++mi)
                        #pragma unroll
                        for (int rr = 0; rr < 4; ++rr)
                            p1[mi][ni][rr] = pref[mi][ni][rr] + off;
                }
            } else {
                // consume h immediately: no h[] array
                if (MODE == 1) {
                    #pragma unroll
                    for (int ni = 0; ni < 2; ++ni) {
                        int col = wc * 32 + ni * 16 + l16;
                        float off = Pbase[(blk << 8) + 128 + col];
                        if (wr) off += aux[col];
                        #pragma unroll
                        for (int mi = 0; mi < 4; ++mi)
                            #pragma unroll
                            for (int rr = 0; rr < 4; ++rr) {
                                long row = rowBase + wr * 64 + mi * 16 + quad * 4 + rr;
                                float h = pref[mi][ni][rr] + off -
                                          fmaxf(p1[mi][ni][rr], 0.f) * g2[mi][ni][rr];
                                Hb[row * HID + col] = (bf16)h;
                            }
                    }
                } else {
                    float w0[2], w1[2], off[2];
                    #pragma unroll
                    for (int ni = 0; ni < 2; ++ni) {
                        int col = wc * 32 + ni * 16 + l16;
                        w0[ni] = Wfc[2 * HID + col];
                        w1[ni] = Wfc[3 * HID + col];
                        off[ni] = Pbase[(blk << 8) + 128 + col];
                        if (wr) off[ni] += aux[col];
                    }
                    #pragma unroll
                    for (int mi = 0; mi < 4; ++mi)
                        #pragma unroll
                        for (int rr = 0; rr < 4; ++rr) {
                            float z0 = 0.f, z1 = 0.f;
                            #pragma unroll
                            for (int ni = 0; ni < 2; ++ni) {
                                float h = pref[mi][ni][rr] + off[ni] -
                                          fmaxf(p1[mi][ni][rr], 0.f) * g2[mi][ni][rr];
                                z0 += h * w0[ni];
                                z1 += h * w1[ni];
                            }
                            z0 += __shfl_xor(z0, 1); z1 += __shfl_xor(z1, 1);
                            z0 += __shfl_xor(z0, 2); z1 += __shfl_xor(z1, 2);
                            z0 += __shfl_xor(z0, 4); z1 += __shfl_xor(z1, 4);
                            z0 += __shfl_xor(z0, 8); z1 += __shfl_xor(z1, 8);
                            if (l16 == 0) {
                                int row = wr * 64 + mi * 16 + quad * 4 + rr;
                                zbuf[wc][row][0] = z0;
                                zbuf[wc][row][1] = z1;
                            }
                        }
                }
            }
        }
    }

    if (MODE == 0) {
        __syncthreads();
        if (tid < 256) Pout[(blk << 8) + tid] = aux[tid] + aux[256 + tid];
    } else if (MODE == 2) {
        __syncthreads();
        float lsum = 0.f;
        if (tid < 128) {
            int row = tid;
            int b = (int)(blk >> 4), chunk = (int)(blk & 15);
            float z0 = zbuf[0][row][0] + zbuf[1][row][0] + zbuf[2][row][0] + zbuf[3][row][0];
            float z1 = zbuf[0][row][1] + zbuf[1][row][1] + zbuf[2][row][1] + zbuf[3][row][1];
            float o1 = fast_sigmoid(z1 - z0);
            float sg = fast_sigmoid(o1);
            float d = xlab[b] - sg;
            if (chunk * CH + row < xlen[b]) lsum = d * d;
            lsum += __shfl_xor(lsum, 1);
            lsum += __shfl_xor(lsum, 2);
            lsum += __shfl_xor(lsum, 4);
            lsum += __shfl_xor(lsum, 8);
            lsum += __shfl_xor(lsum, 16);
            lsum += __shfl_xor(lsum, 32);
            if (lane == 0) red[wid] = lsum;
        }
        __syncthreads();
        if (tid == 0) atomicAdd(out, red[0] + red[1]);
    }
}

// in-place exclusive scan over the NCH chunks, per (b, ch)
__global__ __launch_bounds__(256) void scan_partials_k(float* __restrict__ P) {
    int ch = threadIdx.x;
    long b = blockIdx.x;
    float v[NCH];
    #pragma unroll
    for (int c = 0; c < NCH; ++c) v[c] = P[((b * NCH + c) << 8) + ch];
    float run = 0.f;
    #pragma unroll
    for (int c = 0; c < NCH; ++c) {
        float t = v[c];
        P[((b * NCH + c) << 8) + ch] = run;
        run += t;
    }
}

extern "C" void kernel_launch(void* const* d_in, const int* in_sizes, int n_in,
                              void* d_out, int out_size, void* d_ws, size_t ws_size,
                              hipStream_t stream) {
    const float* x    = (const float*)d_in[0];
    const int*   xlen = (const int*)d_in[1];
    const float* xlab = (const float*)d_in[2];
    const float* Wx2h = (const float*)d_in[3];  // [2,256,128] f32
    const float* Wfc  = (const float*)d_in[4];  // [2,2,128] f32
    float* out = (float*)d_out;

    char* ws = (char*)d_ws;
    bf16*  Hb = (bf16*)ws;                                   // 64 MiB
    float* P  = (float*)(ws + (size_t)MTOT * HID * 2);       // 2 MiB
    bf16*  Wb = (bf16*)((char*)P + (size_t)BATCH * NCH * TWOH * 4);  // 128 KiB

    hipMemsetAsync(d_out, 0, sizeof(float), stream);
    convert_w_k<<<64, 256, 0, stream>>>(Wx2h, Wb);

    // layer 0: pass1 (chunk sums) -> scan -> pass2 (h0 -> Hb)
    fused_k<0, true><<<MTOT / 128, 512, 0, stream>>>(x, Wb, nullptr, P, nullptr,
                                                     nullptr, nullptr, nullptr, nullptr);
    scan_partials_k<<<BATCH, 256, 0, stream>>>(P);
    fused_k<1, true><<<MTOT / 128, 512, 0, stream>>>(x, Wb, P, nullptr, Hb,
                                                     nullptr, nullptr, nullptr, nullptr);
    // layer 1: pass1 -> scan -> pass2 (loss)
    fused_k<0, false><<<MTOT / 128, 512, 0, stream>>>(Hb, Wb + TWOH * HID, nullptr, P,
                                                      nullptr, nullptr, nullptr, nullptr, nullptr);
    scan_partials_k<<<BATCH, 256, 0, stream>>>(P);
    fused_k<2, false><<<MTOT / 128, 512, 0, stream>>>(Hb, Wb + TWOH * HID, P, nullptr,
                                                      nullptr, Wfc, xlen, xlab, out);
}